// Round 3
// baseline (1029.997 us; speedup 1.0000x reference)
//
#include <hip/hip_runtime.h>
#include <hip/hip_bf16.h>

// RiemannianGraph_HRSNN: B=2048 batches, T=15 steps, N=64 nodes. ALL I/O f32
// (reference setup_inputs is jnp.float32; R1/R2 misread as bf16 -> NaN ->
// relu(NaN)=0 -> out=b2=0 -> exact-stub absmax 46.25. This round: float*.)
//
// Rank-1 decomposition: x = Xt*Wp + bp  (per-node scalar times vector), so
//   cur1[n,f]  = Lx[n]*u1[f] + Lsum[n]*cb1[f] + bg1[f]        (Lx = L@Xt)
//   spk1[n,f]  = S1[n,f] + Xt[n]*us1[f] + cs1[f]              (S1 = 3-LIF spike sum)
//   cur2[n,g]  = (L@S1@Wg2)[n,g] + Lx[n]*u2g[g] + Lsum[n]*c2g[g] + bg2[g]
//   skip2[n,g] = (S1@Ws2)[n,g] + Xt[n]*u2s[g] + cs2c[g]
// Dense work per batch-step: M=L@S1 (64x64x32), M@Wg2 (64x32x64), S1@Ws2 (64x32x64).
// Main kernel: 1 block = 1 batch, 256 threads, LIF state in registers.
// LDS = 55,040 B. Decoder: separate kernel, dp (f32, 32 MB) staged through d_ws.

#define LP 68   // L row-major pad (f32): rows 272B (16B-aligned), quads aligned
#define SP 36   // S1 rows pad (144B rows, float4-aligned)
#define MP 36   // M rows pad
#define WP 33   // Wg2t/Ws2t pad: stride 33 -> per-lane column b32 reads conflict-free

#define LIF_STEP(mem, beta, thr, cur, spksum)                \
  {                                                          \
    float r_ = ((mem) > (thr)) ? (thr) : 0.0f;               \
    (mem) = (beta) * (mem) + (cur) - r_;                     \
    (spksum) += (((mem) - (thr)) > 0.0f) ? 1.0f : 0.0f;      \
  }

__global__ __launch_bounds__(256, 2)
void hrsnn_main(const float* __restrict__ Lg,  const float* __restrict__ Xg,
                const float* __restrict__ Wp,  const float* __restrict__ bp,
                const float* __restrict__ Wg1, const float* __restrict__ bg1,
                const float* __restrict__ Ws1, const float* __restrict__ bs1,
                const float* __restrict__ Wg2, const float* __restrict__ bg2,
                const float* __restrict__ Ws2, const float* __restrict__ bs2,
                float* __restrict__ dp_out)
{
  __shared__ __align__(16) float Lf[64][LP];    // L row-major
  __shared__ __align__(16) float S1[64][SP];    // layer-1 spike sums
  __shared__ __align__(16) float Mm[64][MP];    // M = L @ S1
  __shared__ __align__(16) float Wg2t[64][WP];  // Wg2 transposed [g][f]
  __shared__ __align__(16) float Ws2t[64][WP];  // Ws2 transposed [g][f]
  __shared__ float Xt[64], Lx[64], Lsum[64];
  __shared__ float u1[32], cb1[32], us1v[32], cs1v[32];
  __shared__ float u2g[64], c2g[64], u2s[64], cs2c[64];

  const int tid = threadIdx.x;
  const int b = blockIdx.x;

  // ---- stage L (float4: 4 per thread) and transposed layer-2 weights ----
  const float* Lb = Lg + (size_t)b * 4096;
#pragma unroll
  for (int k = 0; k < 4; k++) {
    const int i4 = tid + 256 * k;           // float4 index in [0,1024)
    const float4 v = *(const float4*)&Lb[i4 * 4];
    *(float4*)&Lf[i4 >> 4][(i4 & 15) * 4] = v;
  }
  for (int i = tid; i < 2048; i += 256) {
    int f = i >> 6, g = i & 63;
    Wg2t[g][f] = Wg2[i];
    Ws2t[g][f] = Ws2[i];
  }
  __syncthreads();

  // ---- Lsum[n] = sum_m L[n][m] : 4 lanes per row, float4 + shfl reduce ----
  {
    const int n = tid >> 2, q = tid & 3;
    const int mb = q * 16;
    float p = 0.f;
#pragma unroll
    for (int i = 0; i < 4; i++) {
      const float4 l4 = *(const float4*)&Lf[n][mb + 4 * i];
      p += l4.x + l4.y + l4.z + l4.w;
    }
    p += __shfl_xor(p, 1, 64);
    p += __shfl_xor(p, 2, 64);
    if (q == 0) Lsum[n] = p;
  }

  // ---- derived weight vectors (rank-1 folding of W_proj/b_proj) ----
  if (tid < 32) {
    const int f = tid;
    float a = 0.f, bb = 0.f, c = 0.f, d = 0.f;
    for (int k = 0; k < 16; k++) {
      float wp = Wp[k], bpv = bp[k];
      float wg = Wg1[k * 32 + f], ws = Ws1[k * 32 + f];
      a += wp * wg; bb += bpv * wg;
      c += wp * ws; d += bpv * ws;
    }
    u1[f] = a;  cb1[f] = bb;
    us1v[f] = c; cs1v[f] = d + bs1[f];
  }
  __syncthreads();
  if (tid < 64) {
    const int g = tid;
    float a = 0.f, bb = 0.f, c = 0.f, d = 0.f;
    for (int f = 0; f < 32; f++) {
      float wg = Wg2t[g][f], ws = Ws2t[g][f];
      float uu = us1v[f], cc = cs1v[f];
      a += uu * wg; bb += cc * wg;
      c += uu * ws; d += cc * ws;
    }
    u2g[g] = a; c2g[g] = bb;
    u2s[g] = c; cs2c[g] = d + bs2[g];
  }
  __syncthreads();

  // ---- per-thread cell mapping ----
  const int f1  = tid & 31;   // layer-1 feature; nodes n1b + 8j, j<8
  const int g2  = tid & 63;   // layer-2 feature; nodes n2b + 4j, j<16
  const int n1b = tid >> 5;
  const int n2b = tid >> 6;

  const float u1f = u1[f1], cb1f = cb1[f1], bg1f = bg1[f1];
  const float u2gf = u2g[g2], c2gf = c2g[g2], bg2f = bg2[g2];
  const float u2sf = u2s[g2], cs2f = cs2c[g2];

  float m1a[8], m1n[8], m1m[8];
  float m2a[16], m2n[16], m2m[16], mli[16], aF[16], aL[16];
#pragma unroll
  for (int j = 0; j < 8; j++) { m1a[j] = 0.f; m1n[j] = 0.f; m1m[j] = 0.f; }
#pragma unroll
  for (int j = 0; j < 16; j++) {
    m2a[j] = 0.f; m2n[j] = 0.f; m2m[j] = 0.f;
    mli[j] = 0.f; aF[j] = 0.f; aL[j] = 0.f;
  }

  const float* Xb = Xg + (size_t)b * 15 * 64;
  const int nq = tid >> 2, qq = tid & 3;   // Lx quarter-split mapping

  for (int t = 0; t < 15; t++) {
    // ---- Xt ----
    if (tid < 64) Xt[tid] = Xb[t * 64 + tid];
    __syncthreads();

    // ---- Lx = L @ Xt : 4 lanes per row, float4 + shfl reduce ----
    {
      const int mb = qq * 16;
      float p = 0.f;
#pragma unroll
      for (int i = 0; i < 4; i++) {
        const float4 l4 = *(const float4*)&Lf[nq][mb + 4 * i];
        p += l4.x * Xt[mb + 4 * i + 0] + l4.y * Xt[mb + 4 * i + 1]
           + l4.z * Xt[mb + 4 * i + 2] + l4.w * Xt[mb + 4 * i + 3];
      }
      p += __shfl_xor(p, 1, 64);
      p += __shfl_xor(p, 2, 64);
      if (qq == 0) Lx[nq] = p;
    }
    __syncthreads();

    // ---- layer 1: cur1 rank-1 assembly + triple LIF -> S1 ----
#pragma unroll
    for (int j = 0; j < 8; j++) {
      const int n = n1b + 8 * j;
      const float cur = Lx[n] * u1f + Lsum[n] * cb1f + bg1f;
      float ss = 0.f;
      LIF_STEP(m1a[j], 0.8f, 0.8f, cur, ss);
      LIF_STEP(m1n[j], 0.9f, 1.0f, cur, ss);
      LIF_STEP(m1m[j], 0.95f, 1.5f, cur, ss);
      S1[n][f1] = ss;
    }
    __syncthreads();

    // ---- M = L @ S1  (Lf rows via float4 broadcast, S1 cols 2-way) ----
    float acc[8];
#pragma unroll
    for (int j = 0; j < 8; j++) acc[j] = 0.f;
    for (int m = 0; m < 64; m += 4) {
      const float s0 = S1[m + 0][f1], s1 = S1[m + 1][f1];
      const float s2 = S1[m + 2][f1], s3 = S1[m + 3][f1];
#pragma unroll
      for (int j = 0; j < 8; j++) {
        const float4 l4 = *(const float4*)&Lf[n1b + 8 * j][m];
        acc[j] += l4.x * s0 + l4.y * s1 + l4.z * s2 + l4.w * s3;
      }
    }
#pragma unroll
    for (int j = 0; j < 8; j++) Mm[n1b + 8 * j][f1] = acc[j];
    __syncthreads();

    // ---- cur2 partial (M@Wg2) and skip2 partial (S1@Ws2) ----
    float cacc[16], sacc[16];
#pragma unroll
    for (int j = 0; j < 16; j++) { cacc[j] = 0.f; sacc[j] = 0.f; }
    for (int f = 0; f < 32; f += 4) {
      const float wgA = Wg2t[g2][f + 0], wgB = Wg2t[g2][f + 1];
      const float wgC = Wg2t[g2][f + 2], wgD = Wg2t[g2][f + 3];
      const float wsA = Ws2t[g2][f + 0], wsB = Ws2t[g2][f + 1];
      const float wsC = Ws2t[g2][f + 2], wsD = Ws2t[g2][f + 3];
#pragma unroll
      for (int j = 0; j < 16; j++) {
        const int n = n2b + 4 * j;
        const float4 m4 = *(const float4*)&Mm[n][f];
        const float4 s4 = *(const float4*)&S1[n][f];
        cacc[j] += m4.x * wgA + m4.y * wgB + m4.z * wgC + m4.w * wgD;
        sacc[j] += s4.x * wsA + s4.y * wsB + s4.z * wsC + s4.w * wsD;
      }
    }

    // ---- layer 2 LIF + leaky integrator + DP accumulators ----
    const bool isF = (t < 5), isL = (t >= 10);
#pragma unroll
    for (int j = 0; j < 16; j++) {
      const int n = n2b + 4 * j;
      const float cur2 = cacc[j] + Lx[n] * u2gf + Lsum[n] * c2gf + bg2f;
      float ss = 0.f;
      LIF_STEP(m2a[j], 0.8f, 0.8f, cur2, ss);
      LIF_STEP(m2n[j], 0.9f, 1.0f, cur2, ss);
      LIF_STEP(m2m[j], 0.95f, 1.5f, cur2, ss);
      const float spk2 = ss + sacc[j] + Xt[n] * u2sf + cs2f;
      mli[j] = 0.9f * mli[j] + spk2;
      if (isF) aF[j] += mli[j];
      if (isL) aL[j] += mli[j];
    }
    __syncthreads();
  }

  // ---- dp_feat = (sum_last5 - sum_first5)/5, flat cell = n*64 + g ----
  float* dpb = dp_out + (size_t)b * 4096;
#pragma unroll
  for (int j = 0; j < 16; j++) {
    const int n = n2b + 4 * j;
    dpb[n * 64 + g2] = (aL[j] - aF[j]) * 0.2f;
  }
}

// out = relu(dp @ W1 + b1) @ W2 + b2 ; 512 blocks x 4 batches, split-K over 2 halves.
__global__ __launch_bounds__(256, 2)
void hrsnn_decoder(const float* __restrict__ dp, const float* __restrict__ W1,
                   const float* __restrict__ b1, const float* __restrict__ W2,
                   const float* __restrict__ b2, float* __restrict__ out)
{
  __shared__ float hred[2][4][128];
  __shared__ float hfin[4][128];
  const int tid = threadIdx.x;
  const int k = tid & 127, hf = tid >> 7;
  const int b0 = blockIdx.x * 4;

  const float* d0 = dp + (size_t)(b0 + 0) * 4096;
  const float* d1 = dp + (size_t)(b0 + 1) * 4096;
  const float* d2 = dp + (size_t)(b0 + 2) * 4096;
  const float* d3 = dp + (size_t)(b0 + 3) * 4096;

  float a0 = 0.f, a1 = 0.f, a2 = 0.f, a3 = 0.f;
  const int c0 = hf * 2048;
  for (int c = c0; c < c0 + 2048; c++) {
    const float w = W1[(size_t)c * 128 + k];   // coalesced across lanes
    a0 += d0[c] * w;                           // uniform (broadcast) loads
    a1 += d1[c] * w;
    a2 += d2[c] * w;
    a3 += d3[c] * w;
  }
  hred[hf][0][k] = a0; hred[hf][1][k] = a1;
  hred[hf][2][k] = a2; hred[hf][3][k] = a3;
  __syncthreads();

  if (hf == 0) {
    const float bk = b1[k];
#pragma unroll
    for (int i = 0; i < 4; i++) {
      float h = hred[0][i][k] + hred[1][i][k] + bk;
      hfin[i][k] = h > 0.f ? h : 0.f;
    }
  }
  __syncthreads();

  if (tid < 16) {
    const int i = tid >> 2, o = tid & 3;
    float s = b2[o];
    for (int kk = 0; kk < 128; kk++) s += hfin[i][kk] * W2[kk * 4 + o];
    out[(size_t)(b0 + i) * 4 + o] = s;
  }
}

extern "C" void kernel_launch(void* const* d_in, const int* in_sizes, int n_in,
                              void* d_out, int out_size, void* d_ws, size_t ws_size,
                              hipStream_t stream)
{
  const float* Lg  = (const float*)d_in[0];
  const float* Xg  = (const float*)d_in[1];
  const float* Wp  = (const float*)d_in[2];
  const float* bp  = (const float*)d_in[3];
  const float* Wg1 = (const float*)d_in[4];
  const float* bg1 = (const float*)d_in[5];
  const float* Ws1 = (const float*)d_in[6];
  const float* bs1 = (const float*)d_in[7];
  const float* Wg2 = (const float*)d_in[8];
  const float* bg2 = (const float*)d_in[9];
  const float* Ws2 = (const float*)d_in[10];
  const float* bs2 = (const float*)d_in[11];
  const float* W1  = (const float*)d_in[12];
  const float* b1  = (const float*)d_in[13];
  const float* W2  = (const float*)d_in[14];
  const float* b2  = (const float*)d_in[15];

  float* dp  = (float*)d_ws;        // 2048*4096 f32 = 32 MB scratch
  float* out = (float*)d_out;       // [2048, 4] f32

  hipLaunchKernelGGL(hrsnn_main, dim3(2048), dim3(256), 0, stream,
                     Lg, Xg, Wp, bp, Wg1, bg1, Ws1, bs1, Wg2, bg2, Ws2, bs2, dp);
  hipLaunchKernelGGL(hrsnn_decoder, dim3(512), dim3(256), 0, stream,
                     dp, W1, b1, W2, b2, out);
}

// Round 4
// 850.133 us; speedup vs baseline: 1.2116x; 1.2116x over previous
//
#include <hip/hip_runtime.h>
#include <hip/hip_bf16.h>

// RiemannianGraph_HRSNN, MFMA version. B=2048, T=15, N=64. All I/O f32.
// R3 post-mortem: 900us main kernel is ds_read_b128-throughput-bound
// (384 b128/lane/step x 12cyc x 8 waves x 15 x 8 rounds ~= 920us). Fix: do
// M=L@S1, cur2=M@Wg2, spk2=S1@Ws2, Lx=L@Xt on MFMA (16x16x32 bf16) with
// multi-part bf16 splits for ~fp32 accuracy:
//   L 3-part x S1(exact)            -> 2^-27
//   M 3-part x Wg2 3-part (6 terms) -> ~2^-24
//   S1(exact) x Ws2 2-part          -> 2^-18 (no threshold downstream)
//   L 3-part x Xt 2-part (3 terms)  -> ~2^-17
// Block = 1 batch, 512 threads = 8 waves: wave w -> row-stripe p=w>>1 (16 rows),
// column-half h=w&1. LIF-2 state kept in MFMA C/D register layout.
// MFMA layouts (verified refs in guide): A[row=lane&15][k=8*(lane>>4)+j],
// B[k=8*(lane>>4)+j][col=lane&15], C/D[row=4*(lane>>4)+reg][col=lane&15].

typedef __attribute__((ext_vector_type(8))) short s16x8;
typedef __attribute__((ext_vector_type(4))) float f32x4;
#define MFMA16(a, b, c) __builtin_amdgcn_mfma_f32_16x16x32_bf16(a, b, c, 0, 0, 0)

__device__ __forceinline__ short f2bs(float x) {
  union { __hip_bfloat16 h; short s; } u; u.h = __float2bfloat16(x); return u.s;
}
__device__ __forceinline__ float bs2f(short s) {
  union { short s; __hip_bfloat16 h; } u; u.s = s; return __bfloat162float(u.h);
}

#define LIF_STEP(mem, beta, thr, cur, spksum)                \
  {                                                          \
    float r_ = ((mem) > (thr)) ? (thr) : 0.0f;               \
    (mem) = (beta) * (mem) + (cur) - r_;                     \
    (spksum) += (((mem) - (thr)) > 0.0f) ? 1.0f : 0.0f;      \
  }

#define LFS 68      // Lf row stride (f32 words)
#define RS  36      // S1row / Mrow row stride

__global__ __launch_bounds__(512, 2)
void hrsnn_main(const float* __restrict__ Lg,  const float* __restrict__ Xg,
                const float* __restrict__ Wp,  const float* __restrict__ bp,
                const float* __restrict__ Wg1, const float* __restrict__ bg1,
                const float* __restrict__ Ws1, const float* __restrict__ bs1,
                const float* __restrict__ Wg2, const float* __restrict__ bg2,
                const float* __restrict__ Ws2, const float* __restrict__ bs2,
                float* __restrict__ dp_out)
{
  // UBUF: union of Lf[64][68] (init only, 4352) with S1row[64][36]+Mrow[64][36]
  __shared__ __align__(16) float UBUF[4608];
  float* const Lf    = UBUF;          // init only
  float* const S1row = UBUF;          // [64][RS]
  float* const Mrow  = UBUF + 2304;   // [64][RS]
  __shared__ __align__(16) short WgF[4 * 3 * 64 * 8];   // Wg2 frags [tile][part][lane][8]
  __shared__ __align__(16) unsigned int XtHL[960];      // packed (hi<<16|lo) bf16 of Xt
  __shared__ __align__(16) float Xtf[960];
  __shared__ float LxS[64], LsumS[64];
  __shared__ float u1A[32], cb1A[32], us1v[32], cs1v[32];
  __shared__ float u2gA[64], c2gA[64], u2sA[64], cs2A[64];

  const int tid = threadIdx.x;
  const int b = blockIdx.x;
  const int l = tid & 63, w = tid >> 6;
  const int p = w >> 1, h = w & 1;          // row-stripe / col-half
  const int q = l >> 4, c = l & 15;
  const int R = 16 * p;

  // ================= init 1: stage Lf, Xt (split), small weight folds ========
  const float* Lb = Lg + (size_t)b * 4096;
#pragma unroll
  for (int k = 0; k < 2; k++) {
    const int i4 = tid + 512 * k;                 // float4 index in [0,1024)
    const float4 v = *(const float4*)&Lb[i4 * 4];
    *(float4*)&Lf[(i4 >> 4) * LFS + (i4 & 15) * 4] = v;
  }
  const float* Xb = Xg + (size_t)b * 960;
  for (int i = tid; i < 960; i += 512) {
    const float x = Xb[i];
    const short hs = f2bs(x);
    const short ls = f2bs(x - bs2f(hs));
    XtHL[i] = ((unsigned int)(unsigned short)hs << 16) | (unsigned short)ls;
    Xtf[i] = x;
  }
  if (tid < 32) {
    const int f = tid;
    float a = 0.f, bb = 0.f, cc = 0.f, d = 0.f;
    for (int k = 0; k < 16; k++) {
      const float wp = Wp[k], bpv = bp[k];
      const float wg = Wg1[k * 32 + f], ws = Ws1[k * 32 + f];
      a += wp * wg; bb += bpv * wg;
      cc += wp * ws; d += bpv * ws;
    }
    u1A[f] = a; cb1A[f] = bb;
    us1v[f] = cc; cs1v[f] = d + bs1[f];
  }
  __syncthreads();

  // ================= init 2: Lsum, L A-frags, WgF, Ws2 frags ================
  {
    const int n = tid >> 3, o = tid & 7;
    const float4 a4 = *(const float4*)&Lf[n * LFS + 8 * o];
    const float4 b4 = *(const float4*)&Lf[n * LFS + 8 * o + 4];
    float ps = a4.x + a4.y + a4.z + a4.w + b4.x + b4.y + b4.z + b4.w;
    ps += __shfl_xor(ps, 1, 64);
    ps += __shfl_xor(ps, 2, 64);
    ps += __shfl_xor(ps, 4, 64);
    if (o == 0) LsumS[n] = ps;
  }
  // L A-frags: 3 parts x 2 K-slices (K=64)
  s16x8 Lh[2], Lm[2], Ll[2];
#pragma unroll
  for (int s = 0; s < 2; s++) {
    const float* rp = &Lf[(R + c) * LFS + 32 * s + 8 * q];
    const float4 v0 = *(const float4*)rp;
    const float4 v1 = *(const float4*)(rp + 4);
    float v[8] = {v0.x, v0.y, v0.z, v0.w, v1.x, v1.y, v1.z, v1.w};
#pragma unroll
    for (int j = 0; j < 8; j++) {
      const short hh = f2bs(v[j]);       const float r1 = v[j] - bs2f(hh);
      const short mm = f2bs(r1);         const float r2 = r1 - bs2f(mm);
      Lh[s][j] = hh; Lm[s][j] = mm; Ll[s][j] = f2bs(r2);
    }
  }
  // Wg2 fragment store: wave w builds tile tt=w&3; w<4 -> parts 0,1; w>=4 -> part 2
  {
    const int tt = w & 3;
    float v[8];
#pragma unroll
    for (int j = 0; j < 8; j++) v[j] = Wg2[(8 * q + j) * 64 + 16 * tt + c];
    if (w < 4) {
      s16x8 fh, fm;
#pragma unroll
      for (int j = 0; j < 8; j++) {
        const short hh = f2bs(v[j]);
        fh[j] = hh; fm[j] = f2bs(v[j] - bs2f(hh));
      }
      *(s16x8*)&WgF[((tt * 3 + 0) * 64 + l) * 8] = fh;
      *(s16x8*)&WgF[((tt * 3 + 1) * 64 + l) * 8] = fm;
    } else {
      s16x8 fl;
#pragma unroll
      for (int j = 0; j < 8; j++) {
        const short hh = f2bs(v[j]);     const float r1 = v[j] - bs2f(hh);
        const short mm = f2bs(r1);       const float r2 = r1 - bs2f(mm);
        fl[j] = f2bs(r2);
      }
      *(s16x8*)&WgF[((tt * 3 + 2) * 64 + l) * 8] = fl;
    }
  }
  // Ws2 frags (2-part) for this wave's two g-tiles, in registers
  s16x8 WsH[2], WsL[2];
#pragma unroll
  for (int i = 0; i < 2; i++) {
    const int g0 = 32 * h + 16 * i;
#pragma unroll
    for (int j = 0; j < 8; j++) {
      const float x = Ws2[(8 * q + j) * 64 + g0 + c];
      const short hh = f2bs(x);
      WsH[i][j] = hh; WsL[i][j] = f2bs(x - bs2f(hh));
    }
  }
  __syncthreads();

  // ================= init 3: layer-2 derived vectors =========================
  if (tid < 64) {
    const int g = tid;
    float a = 0.f, bb = 0.f, cc = 0.f, d = 0.f;
    for (int f = 0; f < 32; f++) {
      const float wg = Wg2[f * 64 + g], ws = Ws2[f * 64 + g];
      a += us1v[f] * wg; bb += cs1v[f] * wg;
      cc += us1v[f] * ws; d += cs1v[f] * ws;
    }
    u2gA[g] = a; c2gA[g] = bb; u2sA[g] = cc; cs2A[g] = d + bs2[g];
  }
  __syncthreads();

  // ================= init 4: per-lane constants (registers only) =============
  float u2g2[2], u2s2[2], cs22[2], c2c[2][4];
#pragma unroll
  for (int i = 0; i < 2; i++) {
    const int g = 32 * h + 16 * i + c;
    u2g2[i] = u2gA[g]; u2s2[i] = u2sA[g]; cs22[i] = cs2A[g];
    const float cg = c2gA[g], bg = bg2[g];
#pragma unroll
    for (int r = 0; r < 4; r++) c2c[i][r] = LsumS[R + 4 * q + r] * cg + bg;
  }
  // LIF-1 mapping: f = tid&31, nb = tid>>5, cells n = nb + 16j
  const int f1 = tid & 31, nb = tid >> 5;
  const float u1f = u1A[f1];
  float k1c[4];
  {
    const float cb = cb1A[f1], bg = bg1[f1];
#pragma unroll
    for (int j = 0; j < 4; j++) k1c[j] = LsumS[nb + 16 * j] * cb + bg;
  }

  // ================= state registers =========================================
  float m1a[4], m1n[4], m1m[4];
#pragma unroll
  for (int j = 0; j < 4; j++) { m1a[j] = 0.f; m1n[j] = 0.f; m1m[j] = 0.f; }
  float m2a[2][4], m2n[2][4], m2m[2][4], mli[2][4], dpa[2][4];
#pragma unroll
  for (int i = 0; i < 2; i++)
#pragma unroll
    for (int r = 0; r < 4; r++) {
      m2a[i][r] = 0.f; m2n[i][r] = 0.f; m2m[i][r] = 0.f;
      mli[i][r] = 0.f; dpa[i][r] = 0.f;
    }

  const f32x4 fz = {0.f, 0.f, 0.f, 0.f};
  __syncthreads();   // Lf dead; UBUF becomes S1row/Mrow

  // ================= time loop ==============================================
  for (int t = 0; t < 15; t++) {
    // ---- phase A: Lx = L@Xt via MFMA broadcast (all B-cols = Xt) ----
    f32x4 lx = fz;
#pragma unroll
    for (int s = 0; s < 2; s++) {
      const unsigned int* xw = &XtHL[t * 64 + 32 * s + 8 * q];
      const uint4 w0 = *(const uint4*)xw;
      const uint4 w1 = *(const uint4*)(xw + 4);
      unsigned int wv[8] = {w0.x, w0.y, w0.z, w0.w, w1.x, w1.y, w1.z, w1.w};
      s16x8 bh, bl;
#pragma unroll
      for (int j = 0; j < 8; j++) {
        bh[j] = (short)(wv[j] >> 16);
        bl[j] = (short)(wv[j] & 0xffff);
      }
      lx = MFMA16(Lh[s], bh, lx);
      lx = MFMA16(Lm[s], bh, lx);
      lx = MFMA16(Lh[s], bl, lx);
    }
    if (h == 0 && c == 0) {
#pragma unroll
      for (int r = 0; r < 4; r++) LxS[R + 4 * q + r] = lx[r];
    }
    __syncthreads();   // alpha

    // ---- phase B: layer-1 LIF -> S1row ----
#pragma unroll
    for (int j = 0; j < 4; j++) {
      const int n = nb + 16 * j;
      const float cur = LxS[n] * u1f + k1c[j];
      float ss = 0.f;
      LIF_STEP(m1a[j], 0.8f, 0.8f, cur, ss);
      LIF_STEP(m1n[j], 0.9f, 1.0f, cur, ss);
      LIF_STEP(m1m[j], 0.95f, 1.5f, cur, ss);
      S1row[n * RS + f1] = ss;
    }
    __syncthreads();   // beta

    // ---- phase C: M = L@S1 (3-part L), spk2d = S1@Ws2 (2-part W) ----
    f32x4 macc = fz;
#pragma unroll
    for (int s = 0; s < 2; s++) {
      s16x8 bS;
#pragma unroll
      for (int j = 0; j < 8; j++)
        bS[j] = f2bs(S1row[(32 * s + 8 * q + j) * RS + 16 * h + c]);
      macc = MFMA16(Lh[s], bS, macc);
      macc = MFMA16(Lm[s], bS, macc);
      macc = MFMA16(Ll[s], bS, macc);
    }
#pragma unroll
    for (int r = 0; r < 4; r++) Mrow[(R + 4 * q + r) * RS + 16 * h + c] = macc[r];

    f32x4 sacc[2];
    {
      const float* rp = &S1row[(R + c) * RS + 8 * q];
      const float4 v0 = *(const float4*)rp;
      const float4 v1 = *(const float4*)(rp + 4);
      const float v[8] = {v0.x, v0.y, v0.z, v0.w, v1.x, v1.y, v1.z, v1.w};
      s16x8 aS;
#pragma unroll
      for (int j = 0; j < 8; j++) aS[j] = f2bs(v[j]);
#pragma unroll
      for (int i = 0; i < 2; i++) {
        sacc[i] = MFMA16(aS, WsH[i], fz);
        sacc[i] = MFMA16(aS, WsL[i], sacc[i]);
      }
    }
    __syncthreads();   // gamma

    // ---- phase D: cur2 = M@Wg2 (6-term) + LIF-2 (all in registers) ----
    s16x8 aMh, aMm, aMl;
    {
      const float* rp = &Mrow[(R + c) * RS + 8 * q];
      const float4 v0 = *(const float4*)rp;
      const float4 v1 = *(const float4*)(rp + 4);
      const float v[8] = {v0.x, v0.y, v0.z, v0.w, v1.x, v1.y, v1.z, v1.w};
#pragma unroll
      for (int j = 0; j < 8; j++) {
        const short hh = f2bs(v[j]);     const float r1 = v[j] - bs2f(hh);
        const short mm = f2bs(r1);       const float r2 = r1 - bs2f(mm);
        aMh[j] = hh; aMm[j] = mm; aMl[j] = f2bs(r2);
      }
    }
    float xtn[4];
#pragma unroll
    for (int r = 0; r < 4; r++) xtn[r] = Xtf[t * 64 + R + 4 * q + r];

#pragma unroll
    for (int i = 0; i < 2; i++) {
      const int tt = 2 * h + i;
      const s16x8 bGh = *(const s16x8*)&WgF[((tt * 3 + 0) * 64 + l) * 8];
      const s16x8 bGm = *(const s16x8*)&WgF[((tt * 3 + 1) * 64 + l) * 8];
      const s16x8 bGl = *(const s16x8*)&WgF[((tt * 3 + 2) * 64 + l) * 8];
      f32x4 cacc = fz;
      cacc = MFMA16(aMh, bGh, cacc);
      cacc = MFMA16(aMh, bGm, cacc);
      cacc = MFMA16(aMm, bGh, cacc);
      cacc = MFMA16(aMh, bGl, cacc);
      cacc = MFMA16(aMm, bGm, cacc);
      cacc = MFMA16(aMl, bGh, cacc);
#pragma unroll
      for (int r = 0; r < 4; r++) {
        const float cur2 = cacc[r] + lx[r] * u2g2[i] + c2c[i][r];
        float ss = 0.f;
        LIF_STEP(m2a[i][r], 0.8f, 0.8f, cur2, ss);
        LIF_STEP(m2n[i][r], 0.9f, 1.0f, cur2, ss);
        LIF_STEP(m2m[i][r], 0.95f, 1.5f, cur2, ss);
        const float spk2 = ss + sacc[i][r] + xtn[r] * u2s2[i] + cs22[i];
        mli[i][r] = 0.9f * mli[i][r] + spk2;
      }
    }
    if (t < 5) {
#pragma unroll
      for (int i = 0; i < 2; i++)
#pragma unroll
        for (int r = 0; r < 4; r++) dpa[i][r] -= mli[i][r];
    } else if (t >= 10) {
#pragma unroll
      for (int i = 0; i < 2; i++)
#pragma unroll
        for (int r = 0; r < 4; r++) dpa[i][r] += mli[i][r];
    }
    __syncthreads();   // end-of-step (protects S1row/Mrow/LxS for next iter)
  }

  // ---- dp_feat = (sum_last5 - sum_first5)/5, flat cell = n*64 + g ----
  float* dpb = dp_out + (size_t)b * 4096;
#pragma unroll
  for (int i = 0; i < 2; i++) {
    const int g = 32 * h + 16 * i + c;
#pragma unroll
    for (int r = 0; r < 4; r++) {
      const int n = R + 4 * q + r;
      dpb[n * 64 + g] = dpa[i][r] * 0.2f;
    }
  }
}

// out = relu(dp @ W1 + b1) @ W2 + b2 ; 512 blocks x 4 batches.
// dp broadcast values staged through LDS (R3 version was latency-bound on
// uniform global loads).
__global__ __launch_bounds__(256, 4)
void hrsnn_decoder(const float* __restrict__ dp, const float* __restrict__ W1,
                   const float* __restrict__ b1, const float* __restrict__ W2,
                   const float* __restrict__ b2, float* __restrict__ out)
{
  __shared__ float dsb[2][4][256];
  __shared__ float hred[2][4][128];
  __shared__ float hfin[4][128];
  const int tid = threadIdx.x;
  const int k = tid & 127, hf = tid >> 7;
  const int b0 = blockIdx.x * 4;

  float a0 = 0.f, a1 = 0.f, a2 = 0.f, a3 = 0.f;
  for (int ch = 0; ch < 16; ch += 2) {
    __syncthreads();
#pragma unroll
    for (int u = 0; u < 8; u++) {
      const int hh = u >> 2, bi = u & 3;
      dsb[hh][bi][tid] = dp[(size_t)(b0 + bi) * 4096 + (ch + hh) * 256 + tid];
    }
    __syncthreads();
    const int cbase = (ch + hf) * 256;
    for (int cc = 0; cc < 256; cc++) {
      const float wv = W1[(size_t)(cbase + cc) * 128 + k];
      a0 += dsb[hf][0][cc] * wv;
      a1 += dsb[hf][1][cc] * wv;
      a2 += dsb[hf][2][cc] * wv;
      a3 += dsb[hf][3][cc] * wv;
    }
  }
  hred[hf][0][k] = a0; hred[hf][1][k] = a1;
  hred[hf][2][k] = a2; hred[hf][3][k] = a3;
  __syncthreads();

  if (hf == 0) {
    const float bk = b1[k];
#pragma unroll
    for (int i = 0; i < 4; i++) {
      const float hv = hred[0][i][k] + hred[1][i][k] + bk;
      hfin[i][k] = hv > 0.f ? hv : 0.f;
    }
  }
  __syncthreads();

  if (tid < 16) {
    const int i = tid >> 2, o = tid & 3;
    float s = b2[o];
    for (int kk = 0; kk < 128; kk++) s += hfin[i][kk] * W2[kk * 4 + o];
    out[(size_t)(b0 + i) * 4 + o] = s;
  }
}

extern "C" void kernel_launch(void* const* d_in, const int* in_sizes, int n_in,
                              void* d_out, int out_size, void* d_ws, size_t ws_size,
                              hipStream_t stream)
{
  const float* Lg  = (const float*)d_in[0];
  const float* Xg  = (const float*)d_in[1];
  const float* Wp  = (const float*)d_in[2];
  const float* bp  = (const float*)d_in[3];
  const float* Wg1 = (const float*)d_in[4];
  const float* bg1 = (const float*)d_in[5];
  const float* Ws1 = (const float*)d_in[6];
  const float* bs1 = (const float*)d_in[7];
  const float* Wg2 = (const float*)d_in[8];
  const float* bg2 = (const float*)d_in[9];
  const float* Ws2 = (const float*)d_in[10];
  const float* bs2 = (const float*)d_in[11];
  const float* W1  = (const float*)d_in[12];
  const float* b1  = (const float*)d_in[13];
  const float* W2  = (const float*)d_in[14];
  const float* b2  = (const float*)d_in[15];

  float* dpx = (float*)d_ws;        // 2048*4096 f32 = 32 MB scratch
  float* out = (float*)d_out;       // [2048, 4] f32

  hipLaunchKernelGGL(hrsnn_main, dim3(2048), dim3(512), 0, stream,
                     Lg, Xg, Wp, bp, Wg1, bg1, Ws1, bs1, Wg2, bg2, Ws2, bs2, dpx);
  hipLaunchKernelGGL(hrsnn_decoder, dim3(512), dim3(256), 0, stream,
                     dpx, W1, b1, W2, b2, out);
}

// Round 5
// 472.371 us; speedup vs baseline: 2.1805x; 1.7997x over previous
//
#include <hip/hip_runtime.h>
#include <hip/hip_bf16.h>

// RiemannianGraph_HRSNN, MFMA version. B=2048, T=15, N=64. All I/O f32.
// R4 post-mortem: main ~200us (MFMA conversion worked); decoder 650us,
// latency-serialized (VGPR=32, VALUBusy 6%). R5: decoder rewritten as MFMA
// GEMM (2048x4096x128, 3-term split-bf16); main now emits dp as packed
// split-bf16 uint32 (hi<<16|lo) and drops the end-of-step barrier
// (4 -> 3 barriers/step; safety proof at the loop tail).
//
// Main-kernel math (unchanged from R4):
//   L 3-part x S1(exact)            -> 2^-27
//   M 3-part x Wg2 3-part (6 terms) -> ~2^-24
//   S1(exact) x Ws2 2-part          -> 2^-18 (no threshold downstream)
//   L 3-part x Xt 2-part (3 terms)  -> ~2^-17
// MFMA layouts: A[row=lane&15][k=8*(lane>>4)+j], B[k=8q+j][col=lane&15],
// C/D[row=4*(lane>>4)+reg][col=lane&15].

typedef __attribute__((ext_vector_type(8))) short s16x8;
typedef __attribute__((ext_vector_type(4))) float f32x4;
#define MFMA16(a, b, c) __builtin_amdgcn_mfma_f32_16x16x32_bf16(a, b, c, 0, 0, 0)

__device__ __forceinline__ short f2bs(float x) {
  union { __hip_bfloat16 h; short s; } u; u.h = __float2bfloat16(x); return u.s;
}
__device__ __forceinline__ float bs2f(short s) {
  union { short s; __hip_bfloat16 h; } u; u.s = s; return __bfloat162float(u.h);
}

#define LIF_STEP(mem, beta, thr, cur, spksum)                \
  {                                                          \
    float r_ = ((mem) > (thr)) ? (thr) : 0.0f;               \
    (mem) = (beta) * (mem) + (cur) - r_;                     \
    (spksum) += (((mem) - (thr)) > 0.0f) ? 1.0f : 0.0f;      \
  }

#define LFS 68      // Lf row stride (f32 words)
#define RS  36      // S1row / Mrow row stride

__global__ __launch_bounds__(512, 2)
void hrsnn_main(const float* __restrict__ Lg,  const float* __restrict__ Xg,
                const float* __restrict__ Wp,  const float* __restrict__ bp,
                const float* __restrict__ Wg1, const float* __restrict__ bg1,
                const float* __restrict__ Ws1, const float* __restrict__ bs1,
                const float* __restrict__ Wg2, const float* __restrict__ bg2,
                const float* __restrict__ Ws2, const float* __restrict__ bs2,
                unsigned int* __restrict__ dp_out)
{
  // UBUF: union of Lf[64][68] (init only, 4352) with S1row[64][36]+Mrow[64][36]
  __shared__ __align__(16) float UBUF[4608];
  float* const Lf    = UBUF;          // init only
  float* const S1row = UBUF;          // [64][RS]
  float* const Mrow  = UBUF + 2304;   // [64][RS]
  __shared__ __align__(16) short WgF[4 * 3 * 64 * 8];   // Wg2 frags [tile][part][lane][8]
  __shared__ __align__(16) unsigned int XtHL[960];      // packed (hi<<16|lo) bf16 of Xt
  __shared__ __align__(16) float Xtf[960];
  __shared__ float LxS[64], LsumS[64];
  __shared__ float u1A[32], cb1A[32], us1v[32], cs1v[32];
  __shared__ float u2gA[64], c2gA[64], u2sA[64], cs2A[64];

  const int tid = threadIdx.x;
  const int b = blockIdx.x;
  const int l = tid & 63, w = tid >> 6;
  const int p = w >> 1, h = w & 1;          // row-stripe / col-half
  const int q = l >> 4, c = l & 15;
  const int R = 16 * p;

  // ================= init 1: stage Lf, Xt (split), small weight folds ========
  const float* Lb = Lg + (size_t)b * 4096;
#pragma unroll
  for (int k = 0; k < 2; k++) {
    const int i4 = tid + 512 * k;                 // float4 index in [0,1024)
    const float4 v = *(const float4*)&Lb[i4 * 4];
    *(float4*)&Lf[(i4 >> 4) * LFS + (i4 & 15) * 4] = v;
  }
  const float* Xb = Xg + (size_t)b * 960;
  for (int i = tid; i < 960; i += 512) {
    const float x = Xb[i];
    const short hs = f2bs(x);
    const short ls = f2bs(x - bs2f(hs));
    XtHL[i] = ((unsigned int)(unsigned short)hs << 16) | (unsigned short)ls;
    Xtf[i] = x;
  }
  if (tid < 32) {
    const int f = tid;
    float a = 0.f, bb = 0.f, cc = 0.f, d = 0.f;
    for (int k = 0; k < 16; k++) {
      const float wp = Wp[k], bpv = bp[k];
      const float wg = Wg1[k * 32 + f], ws = Ws1[k * 32 + f];
      a += wp * wg; bb += bpv * wg;
      cc += wp * ws; d += bpv * ws;
    }
    u1A[f] = a; cb1A[f] = bb;
    us1v[f] = cc; cs1v[f] = d + bs1[f];
  }
  __syncthreads();

  // ================= init 2: Lsum, L A-frags, WgF, Ws2 frags ================
  {
    const int n = tid >> 3, o = tid & 7;
    const float4 a4 = *(const float4*)&Lf[n * LFS + 8 * o];
    const float4 b4 = *(const float4*)&Lf[n * LFS + 8 * o + 4];
    float ps = a4.x + a4.y + a4.z + a4.w + b4.x + b4.y + b4.z + b4.w;
    ps += __shfl_xor(ps, 1, 64);
    ps += __shfl_xor(ps, 2, 64);
    ps += __shfl_xor(ps, 4, 64);
    if (o == 0) LsumS[n] = ps;
  }
  // L A-frags: 3 parts x 2 K-slices (K=64)
  s16x8 Lh[2], Lm[2], Ll[2];
#pragma unroll
  for (int s = 0; s < 2; s++) {
    const float* rp = &Lf[(R + c) * LFS + 32 * s + 8 * q];
    const float4 v0 = *(const float4*)rp;
    const float4 v1 = *(const float4*)(rp + 4);
    float v[8] = {v0.x, v0.y, v0.z, v0.w, v1.x, v1.y, v1.z, v1.w};
#pragma unroll
    for (int j = 0; j < 8; j++) {
      const short hh = f2bs(v[j]);       const float r1 = v[j] - bs2f(hh);
      const short mm = f2bs(r1);         const float r2 = r1 - bs2f(mm);
      Lh[s][j] = hh; Lm[s][j] = mm; Ll[s][j] = f2bs(r2);
    }
  }
  // Wg2 fragment store: wave w builds tile tt=w&3; w<4 -> parts 0,1; w>=4 -> part 2
  {
    const int tt = w & 3;
    float v[8];
#pragma unroll
    for (int j = 0; j < 8; j++) v[j] = Wg2[(8 * q + j) * 64 + 16 * tt + c];
    if (w < 4) {
      s16x8 fh, fm;
#pragma unroll
      for (int j = 0; j < 8; j++) {
        const short hh = f2bs(v[j]);
        fh[j] = hh; fm[j] = f2bs(v[j] - bs2f(hh));
      }
      *(s16x8*)&WgF[((tt * 3 + 0) * 64 + l) * 8] = fh;
      *(s16x8*)&WgF[((tt * 3 + 1) * 64 + l) * 8] = fm;
    } else {
      s16x8 fl;
#pragma unroll
      for (int j = 0; j < 8; j++) {
        const short hh = f2bs(v[j]);     const float r1 = v[j] - bs2f(hh);
        const short mm = f2bs(r1);       const float r2 = r1 - bs2f(mm);
        fl[j] = f2bs(r2);
      }
      *(s16x8*)&WgF[((tt * 3 + 2) * 64 + l) * 8] = fl;
    }
  }
  // Ws2 frags (2-part) for this wave's two g-tiles, in registers
  s16x8 WsH[2], WsL[2];
#pragma unroll
  for (int i = 0; i < 2; i++) {
    const int g0 = 32 * h + 16 * i;
#pragma unroll
    for (int j = 0; j < 8; j++) {
      const float x = Ws2[(8 * q + j) * 64 + g0 + c];
      const short hh = f2bs(x);
      WsH[i][j] = hh; WsL[i][j] = f2bs(x - bs2f(hh));
    }
  }
  __syncthreads();

  // ================= init 3: layer-2 derived vectors =========================
  if (tid < 64) {
    const int g = tid;
    float a = 0.f, bb = 0.f, cc = 0.f, d = 0.f;
    for (int f = 0; f < 32; f++) {
      const float wg = Wg2[f * 64 + g], ws = Ws2[f * 64 + g];
      a += us1v[f] * wg; bb += cs1v[f] * wg;
      cc += us1v[f] * ws; d += cs1v[f] * ws;
    }
    u2gA[g] = a; c2gA[g] = bb; u2sA[g] = cc; cs2A[g] = d + bs2[g];
  }
  __syncthreads();

  // ================= init 4: per-lane constants (registers only) =============
  float u2g2[2], u2s2[2], cs22[2], c2c[2][4];
#pragma unroll
  for (int i = 0; i < 2; i++) {
    const int g = 32 * h + 16 * i + c;
    u2g2[i] = u2gA[g]; u2s2[i] = u2sA[g]; cs22[i] = cs2A[g];
    const float cg = c2gA[g], bg = bg2[g];
#pragma unroll
    for (int r = 0; r < 4; r++) c2c[i][r] = LsumS[R + 4 * q + r] * cg + bg;
  }
  // LIF-1 mapping: f = tid&31, nb = tid>>5, cells n = nb + 16j
  const int f1 = tid & 31, nb = tid >> 5;
  const float u1f = u1A[f1];
  float k1c[4];
  {
    const float cb = cb1A[f1], bg = bg1[f1];
#pragma unroll
    for (int j = 0; j < 4; j++) k1c[j] = LsumS[nb + 16 * j] * cb + bg;
  }

  // ================= state registers =========================================
  float m1a[4], m1n[4], m1m[4];
#pragma unroll
  for (int j = 0; j < 4; j++) { m1a[j] = 0.f; m1n[j] = 0.f; m1m[j] = 0.f; }
  float m2a[2][4], m2n[2][4], m2m[2][4], mli[2][4], dpa[2][4];
#pragma unroll
  for (int i = 0; i < 2; i++)
#pragma unroll
    for (int r = 0; r < 4; r++) {
      m2a[i][r] = 0.f; m2n[i][r] = 0.f; m2m[i][r] = 0.f;
      mli[i][r] = 0.f; dpa[i][r] = 0.f;
    }

  const f32x4 fz = {0.f, 0.f, 0.f, 0.f};
  __syncthreads();   // Lf dead; UBUF becomes S1row/Mrow

  // ================= time loop: 3 barriers/step ==============================
  // Barrier safety with no end-of-step barrier: D(t) reads Mrow; C(t+1)
  // writes Mrow only after alpha(t+1)+beta(t+1) -- any thread still in D(t)
  // blocks every other thread at alpha(t+1). Same two-barrier separation
  // covers C(t)'s S1row reads vs B(t+1)'s writes (gamma(t)+alpha(t+1)) and
  // B(t)'s LxS reads vs A(t+1)'s writes (beta(t)+gamma(t)).
  for (int t = 0; t < 15; t++) {
    // ---- phase A: Lx = L@Xt via MFMA broadcast (all B-cols = Xt) ----
    f32x4 lx = fz;
#pragma unroll
    for (int s = 0; s < 2; s++) {
      const unsigned int* xw = &XtHL[t * 64 + 32 * s + 8 * q];
      const uint4 w0 = *(const uint4*)xw;
      const uint4 w1 = *(const uint4*)(xw + 4);
      unsigned int wv[8] = {w0.x, w0.y, w0.z, w0.w, w1.x, w1.y, w1.z, w1.w};
      s16x8 bh, bl;
#pragma unroll
      for (int j = 0; j < 8; j++) {
        bh[j] = (short)(wv[j] >> 16);
        bl[j] = (short)(wv[j] & 0xffff);
      }
      lx = MFMA16(Lh[s], bh, lx);
      lx = MFMA16(Lm[s], bh, lx);
      lx = MFMA16(Lh[s], bl, lx);
    }
    if (h == 0 && c == 0) {
#pragma unroll
      for (int r = 0; r < 4; r++) LxS[R + 4 * q + r] = lx[r];
    }
    __syncthreads();   // alpha

    // ---- phase B: layer-1 LIF -> S1row ----
#pragma unroll
    for (int j = 0; j < 4; j++) {
      const int n = nb + 16 * j;
      const float cur = LxS[n] * u1f + k1c[j];
      float ss = 0.f;
      LIF_STEP(m1a[j], 0.8f, 0.8f, cur, ss);
      LIF_STEP(m1n[j], 0.9f, 1.0f, cur, ss);
      LIF_STEP(m1m[j], 0.95f, 1.5f, cur, ss);
      S1row[n * RS + f1] = ss;
    }
    __syncthreads();   // beta

    // ---- phase C: M = L@S1 (3-part L), spk2d = S1@Ws2 (2-part W) ----
    f32x4 macc = fz;
#pragma unroll
    for (int s = 0; s < 2; s++) {
      s16x8 bS;
#pragma unroll
      for (int j = 0; j < 8; j++)
        bS[j] = f2bs(S1row[(32 * s + 8 * q + j) * RS + 16 * h + c]);
      macc = MFMA16(Lh[s], bS, macc);
      macc = MFMA16(Lm[s], bS, macc);
      macc = MFMA16(Ll[s], bS, macc);
    }
#pragma unroll
    for (int r = 0; r < 4; r++) Mrow[(R + 4 * q + r) * RS + 16 * h + c] = macc[r];

    f32x4 sacc[2];
    {
      const float* rp = &S1row[(R + c) * RS + 8 * q];
      const float4 v0 = *(const float4*)rp;
      const float4 v1 = *(const float4*)(rp + 4);
      const float v[8] = {v0.x, v0.y, v0.z, v0.w, v1.x, v1.y, v1.z, v1.w};
      s16x8 aS;
#pragma unroll
      for (int j = 0; j < 8; j++) aS[j] = f2bs(v[j]);
#pragma unroll
      for (int i = 0; i < 2; i++) {
        sacc[i] = MFMA16(aS, WsH[i], fz);
        sacc[i] = MFMA16(aS, WsL[i], sacc[i]);
      }
    }
    __syncthreads();   // gamma

    // ---- phase D: cur2 = M@Wg2 (6-term) + LIF-2 (all in registers) ----
    s16x8 aMh, aMm, aMl;
    {
      const float* rp = &Mrow[(R + c) * RS + 8 * q];
      const float4 v0 = *(const float4*)rp;
      const float4 v1 = *(const float4*)(rp + 4);
      const float v[8] = {v0.x, v0.y, v0.z, v0.w, v1.x, v1.y, v1.z, v1.w};
#pragma unroll
      for (int j = 0; j < 8; j++) {
        const short hh = f2bs(v[j]);     const float r1 = v[j] - bs2f(hh);
        const short mm = f2bs(r1);       const float r2 = r1 - bs2f(mm);
        aMh[j] = hh; aMm[j] = mm; aMl[j] = f2bs(r2);
      }
    }
    float xtn[4];
#pragma unroll
    for (int r = 0; r < 4; r++) xtn[r] = Xtf[t * 64 + R + 4 * q + r];

#pragma unroll
    for (int i = 0; i < 2; i++) {
      const int tt = 2 * h + i;
      const s16x8 bGh = *(const s16x8*)&WgF[((tt * 3 + 0) * 64 + l) * 8];
      const s16x8 bGm = *(const s16x8*)&WgF[((tt * 3 + 1) * 64 + l) * 8];
      const s16x8 bGl = *(const s16x8*)&WgF[((tt * 3 + 2) * 64 + l) * 8];
      f32x4 cacc = fz;
      cacc = MFMA16(aMh, bGh, cacc);
      cacc = MFMA16(aMh, bGm, cacc);
      cacc = MFMA16(aMm, bGh, cacc);
      cacc = MFMA16(aMh, bGl, cacc);
      cacc = MFMA16(aMm, bGm, cacc);
      cacc = MFMA16(aMl, bGh, cacc);
#pragma unroll
      for (int r = 0; r < 4; r++) {
        const float cur2 = cacc[r] + lx[r] * u2g2[i] + c2c[i][r];
        float ss = 0.f;
        LIF_STEP(m2a[i][r], 0.8f, 0.8f, cur2, ss);
        LIF_STEP(m2n[i][r], 0.9f, 1.0f, cur2, ss);
        LIF_STEP(m2m[i][r], 0.95f, 1.5f, cur2, ss);
        const float spk2 = ss + sacc[i][r] + xtn[r] * u2s2[i] + cs22[i];
        mli[i][r] = 0.9f * mli[i][r] + spk2;
      }
    }
    if (t < 5) {
#pragma unroll
      for (int i = 0; i < 2; i++)
#pragma unroll
        for (int r = 0; r < 4; r++) dpa[i][r] -= mli[i][r];
    } else if (t >= 10) {
#pragma unroll
      for (int i = 0; i < 2; i++)
#pragma unroll
        for (int r = 0; r < 4; r++) dpa[i][r] += mli[i][r];
    }
    // no end-of-step barrier (see proof above)
  }

  // ---- dp_feat = (sum_last5 - sum_first5)/5, packed split-bf16 ----
  unsigned int* dpb = dp_out + (size_t)b * 4096;
#pragma unroll
  for (int i = 0; i < 2; i++) {
    const int g = 32 * h + 16 * i + c;
#pragma unroll
    for (int r = 0; r < 4; r++) {
      const int n = R + 4 * q + r;
      const float v = dpa[i][r] * 0.2f;
      const short hh = f2bs(v);
      const short ll = f2bs(v - bs2f(hh));
      dpb[n * 64 + g] = ((unsigned int)(unsigned short)hh << 16) | (unsigned short)ll;
    }
  }
}

// Decoder: out = relu(dp @ W1 + b1) @ W2 + b2 as an MFMA GEMM.
// 128 blocks x 512 threads; block = 16 batches, wave = one 16-col tile of W1,
// K = 4096 in 128 slices of 32. A from packed split-bf16 dp (2 VALU/elem);
// W1 split in-register (L2-resident, 2 MB); 3-term MFMA (~2^-16 rel).
__global__ __launch_bounds__(512, 1)
void hrsnn_decoder(const unsigned int* __restrict__ dpq, const float* __restrict__ W1,
                   const float* __restrict__ b1, const float* __restrict__ W2,
                   const float* __restrict__ b2, float* __restrict__ out)
{
  __shared__ __align__(16) float H[16][132];   // pad 132 -> <=2-way banks
  const int tid = threadIdx.x;
  const int l = tid & 63, tt = tid >> 6;       // wave = col tile (8 tiles)
  const int q = l >> 4, c = l & 15;

  const unsigned int* arow = dpq + (size_t)(blockIdx.x * 16 + c) * 4096 + 8 * q;
  const float* bcol = W1 + (8 * q) * 128 + 16 * tt + c;

  f32x4 acc = {0.f, 0.f, 0.f, 0.f};
  for (int s = 0; s < 128; s++) {
    const uint4 a0 = *(const uint4*)(arow + 32 * s);
    const uint4 a1 = *(const uint4*)(arow + 32 * s + 4);
    const unsigned int av[8] = {a0.x, a0.y, a0.z, a0.w, a1.x, a1.y, a1.z, a1.w};
    s16x8 Ah, Al, Bh, Bl;
#pragma unroll
    for (int j = 0; j < 8; j++) {
      Ah[j] = (short)(av[j] >> 16);
      Al[j] = (short)(av[j] & 0xffff);
      const float x = bcol[(32 * s + j) * 128];
      const short hh = f2bs(x);
      Bh[j] = hh; Bl[j] = f2bs(x - bs2f(hh));
    }
    acc = MFMA16(Ah, Bh, acc);
    acc = MFMA16(Al, Bh, acc);
    acc = MFMA16(Ah, Bl, acc);
  }

  const float bk = b1[16 * tt + c];
#pragma unroll
  for (int r = 0; r < 4; r++) {
    const float hv = acc[r] + bk;
    H[4 * q + r][16 * tt + c] = hv > 0.f ? hv : 0.f;
  }
  __syncthreads();

  if (tid < 64) {
    const int i = tid >> 2, o = tid & 3;
    float s = b2[o];
    for (int k = 0; k < 128; k++) s += H[i][k] * W2[k * 4 + o];
    out[(size_t)(blockIdx.x * 16 + i) * 4 + o] = s;
  }
}

extern "C" void kernel_launch(void* const* d_in, const int* in_sizes, int n_in,
                              void* d_out, int out_size, void* d_ws, size_t ws_size,
                              hipStream_t stream)
{
  const float* Lg  = (const float*)d_in[0];
  const float* Xg  = (const float*)d_in[1];
  const float* Wp  = (const float*)d_in[2];
  const float* bp  = (const float*)d_in[3];
  const float* Wg1 = (const float*)d_in[4];
  const float* bg1 = (const float*)d_in[5];
  const float* Ws1 = (const float*)d_in[6];
  const float* bs1 = (const float*)d_in[7];
  const float* Wg2 = (const float*)d_in[8];
  const float* bg2 = (const float*)d_in[9];
  const float* Ws2 = (const float*)d_in[10];
  const float* bs2 = (const float*)d_in[11];
  const float* W1  = (const float*)d_in[12];
  const float* b1  = (const float*)d_in[13];
  const float* W2  = (const float*)d_in[14];
  const float* b2  = (const float*)d_in[15];

  unsigned int* dpq = (unsigned int*)d_ws;  // 2048*4096 packed uint = 32 MB
  float* out = (float*)d_out;               // [2048, 4] f32

  hipLaunchKernelGGL(hrsnn_main, dim3(2048), dim3(512), 0, stream,
                     Lg, Xg, Wp, bp, Wg1, bg1, Ws1, bs1, Wg2, bg2, Ws2, bs2, dpq);
  hipLaunchKernelGGL(hrsnn_decoder, dim3(128), dim3(512), 0, stream,
                     dpq, W1, b1, W2, b2, out);
}